// Round 1
// baseline (207.488 us; speedup 1.0000x reference)
//
#include <hip/hip_runtime.h>
#include <math.h>

#define C 100
#define INV_NORM 0.3989422804014327f   // 1/sqrt(2*pi), STD = 1

// One thread per row. Target-distribution side collapses to per-label tables
// built once per block in LDS:
//   wtab[d+99]  = exp(code(d) - inv_norm),  code(d) = inv_norm*exp(-0.5 d^2)
//   A[mu]       = negentropy(mu) = dotc/csum - inv_norm - log(csum)
//   cinv[mu]    = 1/csum(mu)
// kl_row = A[mu] + log(sum_j exp(s_j)) - cinv[mu] * sum_j wtab[j-mu+99]*s_j
// (no max-subtraction needed: scores are N(0,1), |s| < ~6, exp(s) safe in fp32)
__global__ __launch_bounds__(256) void kl_kernel(
    const float* __restrict__ scores,
    const int*   __restrict__ labels,
    float* __restrict__ out, int n, float inv_n)
{
    __shared__ float wtab[2 * C - 1];
    __shared__ float ctab[2 * C - 1];
    __shared__ float Atab[C];
    __shared__ float cinv[C];

    // Phase 1: w(d) and code(d) for d in [-99, 99]
    for (int d = threadIdx.x; d < 2 * C - 1; d += blockDim.x) {
        float dd   = (float)(d - (C - 1));
        float code = INV_NORM * __expf(-0.5f * dd * dd);
        ctab[d] = code;
        wtab[d] = __expf(code - INV_NORM);
    }
    __syncthreads();

    // Phase 2: per-label csum, dotc -> negentropy A and 1/csum
    for (int mu = threadIdx.x; mu < C; mu += blockDim.x) {
        float csum = 0.f, dotc = 0.f;
        for (int j = 0; j < C; ++j) {
            float w = wtab[j - mu + (C - 1)];
            csum += w;
            dotc  = fmaf(w, ctab[j - mu + (C - 1)], dotc);
        }
        Atab[mu] = dotc / csum - INV_NORM - __logf(csum);
        cinv[mu] = 1.0f / csum;
    }
    __syncthreads();

    // Main loop: one row per thread (grid-stride)
    float acc = 0.f;
    int stride = gridDim.x * blockDim.x;
    for (int row = blockIdx.x * blockDim.x + threadIdx.x; row < n; row += stride) {
        const float4* rp = (const float4*)(scores + (size_t)row * C);
        int mu = labels[row];
        const float* wrow = &wtab[(C - 1) - mu];

        float se = 0.f, dot = 0.f;
        #pragma unroll 5
        for (int k = 0; k < C / 4; ++k) {
            float4 v = rp[k];
            int j = 4 * k;
            se += __expf(v.x);
            se += __expf(v.y);
            se += __expf(v.z);
            se += __expf(v.w);
            dot = fmaf(wrow[j + 0], v.x, dot);
            dot = fmaf(wrow[j + 1], v.y, dot);
            dot = fmaf(wrow[j + 2], v.z, dot);
            dot = fmaf(wrow[j + 3], v.w, dot);
        }
        acc += Atab[mu] + __logf(se) - cinv[mu] * dot;
    }

    // Wave-level reduction (wave = 64), one atomic per wave
    #pragma unroll
    for (int off = 32; off > 0; off >>= 1)
        acc += __shfl_xor(acc, off, 64);
    if ((threadIdx.x & 63) == 0)
        atomicAdd(out, acc * inv_n);
}

extern "C" void kernel_launch(void* const* d_in, const int* in_sizes, int n_in,
                              void* d_out, int out_size, void* d_ws, size_t ws_size,
                              hipStream_t stream)
{
    const float* scores = (const float*)d_in[0];
    const int*   labels = (const int*)d_in[1];
    float*       out    = (float*)d_out;

    int n = in_sizes[0] / C;   // 262144

    // d_out is poisoned (0xAA) before every timed launch — zero it first.
    hipMemsetAsync(d_out, 0, sizeof(float) * (size_t)out_size, stream);

    // 1024 blocks x 256 threads = 262144 threads -> exactly 1 row/thread at n=262144;
    // grid-stride keeps it correct for other n. 16 waves/CU for latency hiding.
    kl_kernel<<<1024, 256, 0, stream>>>(scores, labels, out, n, 1.0f / (float)n);
}

// Round 2
// 177.473 us; speedup vs baseline: 1.1691x; 1.1691x over previous
//
#include <hip/hip_runtime.h>
#include <math.h>

#define C 100
#define TILE 64                       // rows per block
#define INV_NORM 0.3989422804014327f  // 1/sqrt(2*pi), STD = 1

// Block = 256 threads, one 64-row tile per block.
// 1) Issue 7 coalesced float4 loads (whole tile, lane-contiguous) into regs.
// 2) Build per-label tables in LDS while loads are in flight:
//      wtab[d+99] = exp(code(d) - inv_norm), code(d) = inv_norm*exp(-d^2/2)
//      Atab[mu]   = dotc/csum - inv_norm - log(csum)   (negentropy of target)
//      cinv[mu]   = 1/csum
// 3) Spill staged regs -> LDS tile, barrier.
// 4) 4 threads/row, 25 elems each from LDS:
//      kl_row = Atab[mu] + log(sum_j exp(s_j)) - cinv[mu] * sum_j wtab[j-mu+99]*s_j
//    (scores ~ N(0,1): |s|<6, exp(s) safe in fp32 without max-subtraction)
// 5) width-4 shuffle -> row term on leader; wave reduce; 1 atomic per block.
__global__ __launch_bounds__(256) void kl_kernel(
    const float* __restrict__ scores,
    const int*   __restrict__ labels,
    float* __restrict__ out, int n, float inv_n)
{
    __shared__ float sTile[TILE * C];          // 25600 B
    __shared__ float wtab[2 * C - 1];
    __shared__ float ctab[2 * C - 1];
    __shared__ float Atab[C];
    __shared__ float cinv[C];
    __shared__ float wsum[4];

    const int tid       = threadIdx.x;
    const int rowInTile = tid >> 2;            // 0..63
    const int part      = tid & 3;             // 0..3
    const int rowBase   = blockIdx.x * TILE;
    const int row       = rowBase + rowInTile;

    // ---- phase A: issue the tile's global loads (fully coalesced) ----
    const float4* gsrc = (const float4*)(scores + (size_t)rowBase * C);
    const int nf4 = (min(TILE, n - rowBase)) * (C / 4);   // float4s in tile
    float4 v[7];
    #pragma unroll
    for (int k = 0; k < 6; ++k) {
        int idx = tid + 256 * k;
        v[k] = (idx < nf4) ? gsrc[idx] : make_float4(0.f, 0.f, 0.f, 0.f);
    }
    {
        int idx = tid + 1536;                  // tail: 64 float4s (wave 0 only)
        v[6] = (idx < nf4) ? gsrc[idx] : make_float4(0.f, 0.f, 0.f, 0.f);
    }
    const int mu = (row < n) ? labels[row] : 0;

    // ---- phase B: per-label tables (overlaps load latency) ----
    for (int d = tid; d < 2 * C - 1; d += 256) {
        float dd   = (float)(d - (C - 1));
        float code = INV_NORM * __expf(-0.5f * dd * dd);
        ctab[d] = code;
        wtab[d] = __expf(code - INV_NORM);
    }
    __syncthreads();
    if (tid < C) {
        const float* wp = &wtab[(C - 1) - tid];
        const float* cp = &ctab[(C - 1) - tid];
        float csum = 0.f, dotc = 0.f;
        for (int j = 0; j < C; ++j) {
            float w = wp[j];
            csum += w;
            dotc  = fmaf(w, cp[j], dotc);
        }
        Atab[tid] = dotc / csum - INV_NORM - __logf(csum);
        cinv[tid] = 1.0f / csum;
    }

    // ---- phase C: staged regs -> LDS tile ----
    float4* st = (float4*)sTile;
    #pragma unroll
    for (int k = 0; k < 6; ++k) st[tid + 256 * k] = v[k];
    if (tid + 1536 < nf4) st[tid + 1536] = v[6];
    __syncthreads();   // covers Atab/cinv writes too

    // ---- phase D: compute. 4 threads/row, 25 contiguous elems each ----
    float acc = 0.f;
    if (row < n) {
        const float* sp = &sTile[rowInTile * C + part * 25];
        const float* wp = &wtab[(C - 1) - mu + part * 25];
        float se = 0.f, dot = 0.f;
        #pragma unroll
        for (int i = 0; i < 25; ++i) {
            float s = sp[i];
            se += __expf(s);
            dot = fmaf(wp[i], s, dot);
        }
        // sum the 4 partials of this row (lanes 4r..4r+3 share a row)
        se  += __shfl_xor(se,  1, 4);  se  += __shfl_xor(se,  2, 4);
        dot += __shfl_xor(dot, 1, 4);  dot += __shfl_xor(dot, 2, 4);
        if (part == 0)
            acc = Atab[mu] + __logf(se) - cinv[mu] * dot;
    }

    // ---- phase E: wave reduce + one atomic per block ----
    #pragma unroll
    for (int off = 32; off > 0; off >>= 1)
        acc += __shfl_xor(acc, off, 64);
    const int wave = tid >> 6, lane = tid & 63;
    if (lane == 0) wsum[wave] = acc;
    __syncthreads();
    if (tid == 0)
        atomicAdd(out, (wsum[0] + wsum[1] + wsum[2] + wsum[3]) * inv_n);
}

extern "C" void kernel_launch(void* const* d_in, const int* in_sizes, int n_in,
                              void* d_out, int out_size, void* d_ws, size_t ws_size,
                              hipStream_t stream)
{
    const float* scores = (const float*)d_in[0];
    const int*   labels = (const int*)d_in[1];
    float*       out    = (float*)d_out;

    int n = in_sizes[0] / C;   // 262144

    // d_out is poisoned (0xAA) before every timed launch — zero it first.
    hipMemsetAsync(d_out, 0, sizeof(float) * (size_t)out_size, stream);

    int blocks = (n + TILE - 1) / TILE;   // 4096
    kl_kernel<<<blocks, 256, 0, stream>>>(scores, labels, out, n, 1.0f / (float)n);
}